// Round 8
// baseline (127.603 us; speedup 1.0000x reference)
//
#include <hip/hip_runtime.h>
#include <math.h>

#define NTH 256   // 4 waves; each thread owns 16 amps (4 register bits)

typedef float v4f __attribute__((ext_vector_type(4)));

// Physical layout: logical float2 index i stored at i + (i>>4): one float2 of
// pad per 16-block => block stride 17 (== 1 mod 16 bank-pairs) => wave64 b64
// accesses hit the bandwidth-optimal 4-lanes-per-bank-pair in all 3 passes.
__device__ __forceinline__ int Ph(int i) { return i + (i >> 4); }

// CNOT-ring basis map (GF(2)-linear, Fr(a^b)=Fr(a)^Fr(b)):
// state_after[Fr(i)] = state_before[i]. Flat bit b holds qubit (11-b).
// Verified R2/R4/R7.
__device__ __forceinline__ int Fr(int i) {
    int x = i; x ^= x >> 1; x ^= x >> 2; x ^= x >> 4; x ^= x >> 8;
    return (x & 0x7FF) | (((x ^ (i >> 11)) & 1) << 11);
}

__device__ __forceinline__ float2 cmul(float2 a, float2 b) {
    return make_float2(a.x*b.x - a.y*b.y, a.x*b.y + a.y*b.x);
}

// Complex 2x2 gate, rows u0,u1 = (u_r0,u_i0,u_r1,u_i1); v0 = bit-clear amp.
__device__ __forceinline__ void apply2(const float4 u0, const float4 u1,
                                       float2& v0, float2& v1) {
    const float n0r = u0.x*v0.x - u0.y*v0.y + u0.z*v1.x - u0.w*v1.y;
    const float n0i = u0.x*v0.y + u0.y*v0.x + u0.z*v1.y + u0.w*v1.x;
    const float n1r = u1.x*v0.x - u1.y*v0.y + u1.z*v1.x - u1.w*v1.y;
    const float n1i = u1.x*v0.y + u1.y*v0.x + u1.z*v1.y + u1.w*v1.x;
    v0 = make_float2(n0r, n0i);
    v1 = make_float2(n1r, n1i);
}

// One LDS trip: 4 gates on flat bits SH+3..SH (qubits 8-SH..11-SH).
// MODE 0: write back to dst at same indices (src==dst => in place).
// MODE 1: ring-fold scatter into dst (dst is the OTHER buffer — no barrier
//         needed between read and scatter).
// MODE 2: no write — accumulate 12 signed probability partials with the
//         ring fold applied to the logical index.
template<int SH, int MODE>
__device__ __forceinline__ void do_pass16(const float2* __restrict__ src,
                                          float2* __restrict__ dst,
                                          const float4 (*gmat)[2],
                                          int gbase, int t, float* zacc) {
    int base;
    if      (SH == 0) base = t << 4;                       // i = t<<4 | r
    else if (SH == 4) base = ((t >> 4) << 8) | (t & 15);   // i = hi|r<<4|lo
    else              base = t;                            // i = r<<8 | t

    float2 v[16];
    #pragma unroll
    for (int r = 0; r < 16; ++r) v[r] = src[Ph(base | (r << SH))];
    #pragma unroll
    for (int k = 3; k >= 0; --k) {
        const int q = 11 - (SH + k);            // qubit of flat bit SH+k
        const float4 u0 = gmat[gbase + q][0];
        const float4 u1 = gmat[gbase + q][1];
        #pragma unroll
        for (int r = 0; r < 16; ++r)
            if (!(r & (1 << k))) apply2(u0, u1, v[r], v[r | (1 << k)]);
    }
    if (MODE == 0) {
        #pragma unroll
        for (int r = 0; r < 16; ++r) dst[Ph(base | (r << SH))] = v[r];
    } else if (MODE == 1) {
        #pragma unroll
        for (int r = 0; r < 16; ++r) dst[Ph(Fr(base | (r << SH)))] = v[r];
    } else {
        #pragma unroll
        for (int r = 0; r < 16; ++r) {
            const int x = Fr(base | (r << SH));     // final logical index
            const float p = v[r].x*v[r].x + v[r].y*v[r].y;
            #pragma unroll
            for (int q2 = 0; q2 < 12; ++q2)
                zacc[q2] += ((x >> (11 - q2)) & 1) ? -p : p;
        }
    }
}

__global__ __launch_bounds__(NTH) void circuit_kernel(
    const float* __restrict__ qw,   // (3,12,3)
    const float* __restrict__ W1,   // (32,12)
    const float* __restrict__ b1,   // (32,)
    const float* __restrict__ W2,   // (16,32)
    const float* __restrict__ b2,   // (16,)
    float* __restrict__ pix)        // 16 outputs -> d_ws
{
    __shared__ float2 ampA[4352];    // 4096 + 256 pad (34 KiB)
    __shared__ float2 ampB[4352];    // double buffer for the ring scatter
    __shared__ float4 gmat[36][2];   // U = RZ*RY*RX rows per gate
    __shared__ float  zp2[48];       // per-wave qubit partials (4 waves x 12)

    const int tid  = threadIdx.x;
    const int lane = tid & 63;
    const int wv   = tid >> 6;

    // ---- preload MLP weights early (latency hidden behind the circuit) ----
    float W1row[12], W2row[32], b1v = 0.f, b2v = 0.f;
    #pragma unroll
    for (int k = 0; k < 12; ++k) W1row[k] = 0.f;
    #pragma unroll
    for (int k = 0; k < 32; ++k) W2row[k] = 0.f;
    if (tid < 32) {
        b1v = b1[tid];
        #pragma unroll
        for (int k = 0; k < 12; ++k) W1row[k] = W1[tid*12 + k];
    }
    if (tid < 16) {
        b2v = b2[tid];
        #pragma unroll
        for (int k = 0; k < 32; ++k) W2row[k] = W2[tid*32 + k];
    }

    // ---- build the 36 gate matrices (one thread per gate) ----
    if (tid < 36) {
        float sx, cx, sy, cy, sz, cz;
        sincosf(0.5f * qw[tid*3+0], &sx, &cx);
        sincosf(0.5f * qw[tid*3+1], &sy, &cy);
        sincosf(0.5f * qw[tid*3+2], &sz, &cz);
        const float a00r =  cy*cx, a00i =  sy*sx;    // A = RY @ RX
        const float a01r = -sy*cx, a01i = -cy*sx;
        const float a10r =  sy*cx, a10i = -cy*sx;
        const float a11r =  cy*cx, a11i = -sy*sx;
        gmat[tid][0] = make_float4(cz*a00r + sz*a00i, cz*a00i - sz*a00r,
                                   cz*a01r + sz*a01i, cz*a01i - sz*a01r);
        gmat[tid][1] = make_float4(cz*a10r - sz*a10i, cz*a10i + sz*a10r,
                                   cz*a11r - sz*a11i, cz*a11i + sz*a11r);
    }
    __syncthreads();                                    // B1

    // ---- layer 1 = product state from |0..0>, built in registers; ring R1
    //      folded into the scatter write. i = (t<<4)|r; flat bit b>=4 comes
    //      from t bit (b-4); r bits 3..0 are qubits 8,9,10,11. ----
    {
        float2 pp = make_float2(1.f, 0.f);
        #pragma unroll
        for (int b = 11; b >= 4; --b) {                 // qubits 0..7
            const int q = 11 - b;
            const float4 g = gmat[q][(tid >> (b - 4)) & 1];
            pp = cmul(pp, make_float2(g.x, g.y));       // column 0
        }
        float2 c8[2], c9[2], c10[2], c11[2];
        #pragma unroll
        for (int s = 0; s < 2; ++s) {
            c8[s]  = make_float2(gmat[8][s].x,  gmat[8][s].y);
            c9[s]  = make_float2(gmat[9][s].x,  gmat[9][s].y);
            c10[s] = make_float2(gmat[10][s].x, gmat[10][s].y);
            c11[s] = make_float2(gmat[11][s].x, gmat[11][s].y);
        }
        float2 hi[4], lo[4];
        #pragma unroll
        for (int s = 0; s < 4; ++s) {
            hi[s] = cmul(c8[(s >> 1) & 1],  c9[s & 1]);
            lo[s] = cmul(c10[(s >> 1) & 1], c11[s & 1]);
        }
        #pragma unroll
        for (int r = 0; r < 16; ++r) {
            const float2 v = cmul(pp, cmul(hi[r >> 2], lo[r & 3]));
            ampA[Ph(Fr((tid << 4) | r))] = v;
        }
    }
    __syncthreads();                                    // B2

    float zacc[12];
    #pragma unroll
    for (int q = 0; q < 12; ++q) zacc[q] = 0.f;

    // ---- layer 2 (gates 12..23): 3 trips; ring R2 scattered into ampB ----
    do_pass16<0,0>(ampA, ampA, gmat, 12, tid, zacc); __syncthreads();  // B3
    do_pass16<4,0>(ampA, ampA, gmat, 12, tid, zacc); __syncthreads();  // B4
    do_pass16<8,1>(ampA, ampB, gmat, 12, tid, zacc); __syncthreads();  // B5
    // ---- layer 3 (gates 24..35): 3 trips; last trip emits partials ----
    do_pass16<0,0>(ampB, ampB, gmat, 24, tid, zacc); __syncthreads();  // B6
    do_pass16<4,0>(ampB, ampB, gmat, 24, tid, zacc); __syncthreads();  // B7
    do_pass16<8,2>(ampB, ampB, gmat, 24, tid, zacc);

    // ---- in-wave reduction (verified R4/R7) ----
    float z6[6];
    #pragma unroll
    for (int k = 0; k < 6; ++k) {
        const float send = (lane & 1) ? zacc[k]   : zacc[k+6];
        const float keep = (lane & 1) ? zacc[k+6] : zacc[k];
        z6[k] = keep + __shfl_xor(send, 1);
    }
    float z3[3];
    #pragma unroll
    for (int k = 0; k < 3; ++k) {
        const float send = (lane & 2) ? z6[k]   : z6[k+3];
        const float keep = (lane & 2) ? z6[k+3] : z6[k];
        z3[k] = keep + __shfl_xor(send, 2);
    }
    #pragma unroll
    for (int m = 4; m <= 32; m <<= 1) {
        #pragma unroll
        for (int k = 0; k < 3; ++k) z3[k] += __shfl_xor(z3[k], m);
    }
    if (lane < 4) {
        const int qb = 6*(lane & 1) + 3*((lane >> 1) & 1);
        #pragma unroll
        for (int k = 0; k < 3; ++k) zp2[wv*12 + qb + k] = z3[k];
    }
    __syncthreads();                                    // B8

    // ---- MLP entirely in wave 0 via shuffle broadcasts (verified R7) ----
    if (tid < 64) {
        float s = 0.f;
        if (tid < 12) {
            #pragma unroll
            for (int w4 = 0; w4 < 4; ++w4) s += zp2[w4*12 + tid];
        }
        float acc = b1v;                       // valid rows for lanes <32
        #pragma unroll
        for (int k = 0; k < 12; ++k) acc += W1row[k] * __shfl(s, k);
        const float h = acc > 0.f ? acc : 0.f;
        float acc2 = b2v;
        #pragma unroll
        for (int k = 0; k < 32; ++k) acc2 += W2row[k] * __shfl(h, k);
        if (tid < 16) pix[tid] = 1.f / (1.f + expf(-acc2));
    }
}

// ---------------------------------------------------------------------------
// Kernel B: broadcast 16 floats to (B,1,4,4) = 64 MiB, nontemporal stores
// via native clang vector type (HIP float4 is rejected by the builtin).
// ---------------------------------------------------------------------------
__global__ __launch_bounds__(256) void bcast_kernel(
    const v4f* __restrict__ pix4, v4f* __restrict__ out4)
{
    const int i = blockIdx.x * 256 + threadIdx.x;
    const v4f val = pix4[i & 3];
    __builtin_nontemporal_store(val, &out4[i]);
}

extern "C" void kernel_launch(void* const* d_in, const int* in_sizes, int n_in,
                              void* d_out, int out_size, void* d_ws, size_t ws_size,
                              hipStream_t stream) {
    // inputs: 0=images (ignored), 1=qweights, 2=W1, 3=b1, 4=W2, 5=b2
    const float* qw = (const float*)d_in[1];
    const float* W1 = (const float*)d_in[2];
    const float* b1 = (const float*)d_in[3];
    const float* W2 = (const float*)d_in[4];
    const float* b2 = (const float*)d_in[5];
    float* pix = (float*)d_ws;   // 16 floats of scratch

    circuit_kernel<<<1, NTH, 0, stream>>>(qw, W1, b1, W2, b2, pix);

    const int n4 = out_size / 4;               // 4,194,304 float4
    bcast_kernel<<<n4 / 256, 256, 0, stream>>>((const v4f*)pix,
                                               (v4f*)d_out);
}

// Round 9
// 126.218 us; speedup vs baseline: 1.0110x; 1.0110x over previous
//
#include <hip/hip_runtime.h>
#include <math.h>

#define NTH 512   // 8 waves (2/SIMD): measured optimum — latency hiding beats
                  // fewer barriers (R8: 4 waves regressed +4.3us) and beats
                  // shuffle-gates (R6: DS-op cost regressed +4.7us)

typedef float v4f __attribute__((ext_vector_type(4)));

// Storage swizzle: logical amp i lives at amp[Sw(i)] (bank spread for the
// strided passes). Self-inverse on bits 0-2.
__device__ __forceinline__ int Sw(int i) { return i ^ ((i >> 6) & 7); }

// CNOT-ring basis map (GF(2)-linear): state_after[Fr(i)] = state_before[i].
// Flat bit b holds qubit (11-b). Verified R2/R4/R7.
__device__ __forceinline__ int Fr(int i) {
    int x = i; x ^= x >> 1; x ^= x >> 2; x ^= x >> 4; x ^= x >> 8;
    return (x & 0x7FF) | (((x ^ (i >> 11)) & 1) << 11);
}

__device__ __forceinline__ float2 cmul(float2 a, float2 b) {
    return make_float2(a.x*b.x - a.y*b.y, a.x*b.y + a.y*b.x);
}

// Complex 2x2 gate, rows u0,u1 = (u_r0,u_i0,u_r1,u_i1); v0 = bit-clear amp.
__device__ __forceinline__ void apply2(const float4 u0, const float4 u1,
                                       float2& v0, float2& v1) {
    const float n0r = u0.x*v0.x - u0.y*v0.y + u0.z*v1.x - u0.w*v1.y;
    const float n0i = u0.x*v0.y + u0.y*v0.x + u0.z*v1.y + u0.w*v1.x;
    const float n1r = u1.x*v0.x - u1.y*v0.y + u1.z*v1.x - u1.w*v1.y;
    const float n1i = u1.x*v0.y + u1.y*v0.x + u1.z*v1.y + u1.w*v1.x;
    v0 = make_float2(n0r, n0i);
    v1 = make_float2(n1r, n1i);
}

// One LDS pass: 3 gates on flat bits PLOW+2..PLOW (qubits 9-PLOW..11-PLOW).
// MODE 0: in-place writeback (src==dst).
// MODE 1: ring-fold scatter into dst — dst is the OTHER buffer, so no
//         barrier is needed between read and scatter (R8-verified pattern).
// MODE 2: no writeback — accumulate 12 signed probability partials using the
//         ring-folded logical index. (All verified R4/R7/R8.)
template<int PLOW, int MODE>
__device__ __forceinline__ void do_pass(const float2* __restrict__ src,
                                        float2* __restrict__ dst,
                                        const float4 (*gmat)[2],
                                        int gbase, int t, float* zacc) {
    int base;
    if      (PLOW == 9) base = t;
    else if (PLOW == 6) base = ((t >> 6) << 9) | (t & 63);
    else if (PLOW == 3) base = ((t >> 3) << 6) | (t & 7);
    else                base = t << 3;

    float2 v[8]; int idx[8];
    #pragma unroll
    for (int r = 0; r < 8; ++r) {
        idx[r] = Sw(base | (r << PLOW));
        v[r] = src[idx[r]];
    }
    #pragma unroll
    for (int k = 2; k >= 0; --k) {
        const int q = 11 - (PLOW + k);          // qubit of flat bit PLOW+k
        const float4 u0 = gmat[gbase + q][0];
        const float4 u1 = gmat[gbase + q][1];
        const int m = 1 << k;
        #pragma unroll
        for (int r = 0; r < 8; ++r)
            if (!(r & m)) apply2(u0, u1, v[r], v[r | m]);
    }
    if (MODE == 0) {
        #pragma unroll
        for (int r = 0; r < 8; ++r) dst[idx[r]] = v[r];
    } else if (MODE == 1) {
        #pragma unroll
        for (int r = 0; r < 8; ++r) dst[Sw(Fr(base | (r << PLOW)))] = v[r];
    } else {
        #pragma unroll
        for (int r = 0; r < 8; ++r) {
            const int x = Fr(base | (r << PLOW));   // final logical index
            const float p = v[r].x*v[r].x + v[r].y*v[r].y;
            #pragma unroll
            for (int q2 = 0; q2 < 12; ++q2)
                zacc[q2] += ((x >> (11 - q2)) & 1) ? -p : p;
        }
    }
}

__global__ __launch_bounds__(NTH) void circuit_kernel(
    const float* __restrict__ qw,   // (3,12,3)
    const float* __restrict__ W1,   // (32,12)
    const float* __restrict__ b1,   // (32,)
    const float* __restrict__ W2,   // (16,32)
    const float* __restrict__ b2,   // (16,)
    float* __restrict__ pix)        // 16 outputs -> d_ws
{
    __shared__ float2 ampA[4096];    // 32 KiB, swizzled storage
    __shared__ float2 ampB[4096];    // double buffer for the ring scatter
    __shared__ float4 gmat[36][2];   // U = RZ*RY*RX rows per gate
    __shared__ float  zp2[96];       // per-wave qubit partials (8 waves x 12)

    const int tid  = threadIdx.x;
    const int lane = tid & 63;
    const int wv   = tid >> 6;

    // ---- preload MLP weights early (latency hidden behind the circuit) ----
    float W1row[12], W2row[32], b1v = 0.f, b2v = 0.f;
    #pragma unroll
    for (int k = 0; k < 12; ++k) W1row[k] = 0.f;
    #pragma unroll
    for (int k = 0; k < 32; ++k) W2row[k] = 0.f;
    if (tid < 32) {
        b1v = b1[tid];
        #pragma unroll
        for (int k = 0; k < 12; ++k) W1row[k] = W1[tid*12 + k];
    }
    if (tid < 16) {
        b2v = b2[tid];
        #pragma unroll
        for (int k = 0; k < 32; ++k) W2row[k] = W2[tid*32 + k];
    }

    // ---- build the 36 gate matrices (one thread per gate) ----
    if (tid < 36) {
        float sx, cx, sy, cy, sz, cz;
        sincosf(0.5f * qw[tid*3+0], &sx, &cx);
        sincosf(0.5f * qw[tid*3+1], &sy, &cy);
        sincosf(0.5f * qw[tid*3+2], &sz, &cz);
        const float a00r =  cy*cx, a00i =  sy*sx;    // A = RY @ RX
        const float a01r = -sy*cx, a01i = -cy*sx;
        const float a10r =  sy*cx, a10i = -cy*sx;
        const float a11r =  cy*cx, a11i = -sy*sx;
        gmat[tid][0] = make_float4(cz*a00r + sz*a00i, cz*a00i - sz*a00r,
                                   cz*a01r + sz*a01i, cz*a01i - sz*a01r);
        gmat[tid][1] = make_float4(cz*a10r - sz*a10i, cz*a10i + sz*a10r,
                                   cz*a11r - sz*a11i, cz*a11i + sz*a11r);
    }
    __syncthreads();                                    // B1

    // ---- layer 1 = product state from |0..0>, built in registers; ring R1
    //      folded into the scatter write (verified R4/R7) ----
    {
        float2 pp = make_float2(1.f, 0.f);
        #pragma unroll
        for (int b = 11; b >= 3; --b) {                 // i bit b = tid bit b-3
            const int q = 11 - b;
            const float4 g = gmat[q][(tid >> (b - 3)) & 1];
            pp = cmul(pp, make_float2(g.x, g.y));       // column 0
        }
        float2 c9[2], c10[2], c11[2];
        #pragma unroll
        for (int s = 0; s < 2; ++s) {
            c9[s]  = make_float2(gmat[9][s].x,  gmat[9][s].y);
            c10[s] = make_float2(gmat[10][s].x, gmat[10][s].y);
            c11[s] = make_float2(gmat[11][s].x, gmat[11][s].y);
        }
        #pragma unroll
        for (int r = 0; r < 8; ++r) {
            const float2 v = cmul(pp,
                cmul(c9[(r>>2)&1], cmul(c10[(r>>1)&1], c11[r&1])));
            ampA[Sw(Fr((tid << 3) | r))] = v;
        }
    }
    __syncthreads();                                    // B2

    float zacc[12];
    #pragma unroll
    for (int q = 0; q < 12; ++q) zacc[q] = 0.f;

    // ---- layer 2 (gates 12..23): 4 passes; ring R2 scattered into ampB
    //      (no mid-pass barrier needed — different destination buffer) ----
    do_pass<9,0>(ampA, ampA, gmat, 12, tid, zacc); __syncthreads();  // B3
    do_pass<6,0>(ampA, ampA, gmat, 12, tid, zacc); __syncthreads();  // B4
    do_pass<3,0>(ampA, ampA, gmat, 12, tid, zacc); __syncthreads();  // B5
    do_pass<0,1>(ampA, ampB, gmat, 12, tid, zacc); __syncthreads();  // B6
    // ---- layer 3 (gates 24..35): last pass emits partials, no writeback ----
    do_pass<9,0>(ampB, ampB, gmat, 24, tid, zacc); __syncthreads();  // B7
    do_pass<6,0>(ampB, ampB, gmat, 24, tid, zacc); __syncthreads();  // B8
    do_pass<3,0>(ampB, ampB, gmat, 24, tid, zacc); __syncthreads();  // B9
    do_pass<0,2>(ampB, ampB, gmat, 24, tid, zacc);

    // ---- in-wave reduction (verified R4/R7) ----
    float z6[6];
    #pragma unroll
    for (int k = 0; k < 6; ++k) {
        const float send = (lane & 1) ? zacc[k]   : zacc[k+6];
        const float keep = (lane & 1) ? zacc[k+6] : zacc[k];
        z6[k] = keep + __shfl_xor(send, 1);
    }
    float z3[3];
    #pragma unroll
    for (int k = 0; k < 3; ++k) {
        const float send = (lane & 2) ? z6[k]   : z6[k+3];
        const float keep = (lane & 2) ? z6[k+3] : z6[k];
        z3[k] = keep + __shfl_xor(send, 2);
    }
    #pragma unroll
    for (int m = 4; m <= 32; m <<= 1) {
        #pragma unroll
        for (int k = 0; k < 3; ++k) z3[k] += __shfl_xor(z3[k], m);
    }
    if (lane < 4) {
        const int qb = 6*(lane & 1) + 3*((lane >> 1) & 1);
        #pragma unroll
        for (int k = 0; k < 3; ++k) zp2[wv*12 + qb + k] = z3[k];
    }
    __syncthreads();                                    // B10

    // ---- MLP entirely in wave 0 via shuffle broadcasts (verified R7) ----
    if (tid < 64) {
        float s = 0.f;
        if (tid < 12) {
            #pragma unroll
            for (int w8 = 0; w8 < 8; ++w8) s += zp2[w8*12 + tid];
        }
        float acc = b1v;                       // valid rows for lanes <32
        #pragma unroll
        for (int k = 0; k < 12; ++k) acc += W1row[k] * __shfl(s, k);
        const float h = acc > 0.f ? acc : 0.f;
        float acc2 = b2v;
        #pragma unroll
        for (int k = 0; k < 32; ++k) acc2 += W2row[k] * __shfl(h, k);
        if (tid < 16) pix[tid] = 1.f / (1.f + expf(-acc2));
    }
}

// ---------------------------------------------------------------------------
// Kernel B: broadcast 16 floats to (B,1,4,4) = 64 MiB, nontemporal stores
// via native clang vector type (HIP float4 is rejected by the builtin).
// ---------------------------------------------------------------------------
__global__ __launch_bounds__(256) void bcast_kernel(
    const v4f* __restrict__ pix4, v4f* __restrict__ out4)
{
    const int i = blockIdx.x * 256 + threadIdx.x;
    const v4f val = pix4[i & 3];
    __builtin_nontemporal_store(val, &out4[i]);
}

extern "C" void kernel_launch(void* const* d_in, const int* in_sizes, int n_in,
                              void* d_out, int out_size, void* d_ws, size_t ws_size,
                              hipStream_t stream) {
    // inputs: 0=images (ignored), 1=qweights, 2=W1, 3=b1, 4=W2, 5=b2
    const float* qw = (const float*)d_in[1];
    const float* W1 = (const float*)d_in[2];
    const float* b1 = (const float*)d_in[3];
    const float* W2 = (const float*)d_in[4];
    const float* b2 = (const float*)d_in[5];
    float* pix = (float*)d_ws;   // 16 floats of scratch

    circuit_kernel<<<1, NTH, 0, stream>>>(qw, W1, b1, W2, b2, pix);

    const int n4 = out_size / 4;               // 4,194,304 float4
    bcast_kernel<<<n4 / 256, 256, 0, stream>>>((const v4f*)pix,
                                               (v4f*)d_out);
}

// Round 10
// 123.904 us; speedup vs baseline: 1.0299x; 1.0187x over previous
//
#include <hip/hip_runtime.h>
#include <math.h>

#define NTH 512   // 8 waves (2/SIMD): measured optimum — latency hiding beats
                  // fewer barriers (R8: 4 waves +4.3us) and shuffle-gates
                  // (R6: +4.7us) and LDS double-buffer (R9: +2.9us)

typedef float v4f __attribute__((ext_vector_type(4)));

// Storage swizzle: logical amp i lives at amp[Sw(i)] (bank spread for the
// strided passes). Self-inverse on bits 0-2.
__device__ __forceinline__ int Sw(int i) { return i ^ ((i >> 6) & 7); }

// CNOT-ring basis map (GF(2)-linear): state_after[Fr(i)] = state_before[i].
// Flat bit b holds qubit (11-b). Verified R2/R4/R7.
__device__ __forceinline__ int Fr(int i) {
    int x = i; x ^= x >> 1; x ^= x >> 2; x ^= x >> 4; x ^= x >> 8;
    return (x & 0x7FF) | (((x ^ (i >> 11)) & 1) << 11);
}

__device__ __forceinline__ float2 cmul(float2 a, float2 b) {
    return make_float2(a.x*b.x - a.y*b.y, a.x*b.y + a.y*b.x);
}

// Complex 2x2 gate, rows u0,u1 = (u_r0,u_i0,u_r1,u_i1); v0 = bit-clear amp.
__device__ __forceinline__ void apply2(const float4 u0, const float4 u1,
                                       float2& v0, float2& v1) {
    const float n0r = u0.x*v0.x - u0.y*v0.y + u0.z*v1.x - u0.w*v1.y;
    const float n0i = u0.x*v0.y + u0.y*v0.x + u0.z*v1.y + u0.w*v1.x;
    const float n1r = u1.x*v0.x - u1.y*v0.y + u1.z*v1.x - u1.w*v1.y;
    const float n1i = u1.x*v0.y + u1.y*v0.x + u1.z*v1.y + u1.w*v1.x;
    v0 = make_float2(n0r, n0i);
    v1 = make_float2(n1r, n1i);
}

// One LDS pass: 3 gates on flat bits PLOW+2..PLOW (qubits 9-PLOW..11-PLOW).
// MODE 0: in-place writeback. MODE 1: ring-fold scatter write (barrier first).
// MODE 2: no writeback — accumulate 12 signed probability partials using the
// ring-folded logical index. (All verified R4/R7.)
template<int PLOW, int MODE>
__device__ __forceinline__ void do_pass(float2* amp, const float4 (*gmat)[2],
                                        int gbase, int t, float* zacc) {
    int base;
    if      (PLOW == 9) base = t;
    else if (PLOW == 6) base = ((t >> 6) << 9) | (t & 63);
    else if (PLOW == 3) base = ((t >> 3) << 6) | (t & 7);
    else                base = t << 3;

    float2 v[8]; int idx[8];
    #pragma unroll
    for (int r = 0; r < 8; ++r) {
        idx[r] = Sw(base | (r << PLOW));
        v[r] = amp[idx[r]];
    }
    #pragma unroll
    for (int k = 2; k >= 0; --k) {
        const int q = 11 - (PLOW + k);          // qubit of flat bit PLOW+k
        const float4 u0 = gmat[gbase + q][0];
        const float4 u1 = gmat[gbase + q][1];
        const int m = 1 << k;
        #pragma unroll
        for (int r = 0; r < 8; ++r)
            if (!(r & m)) apply2(u0, u1, v[r], v[r | m]);
    }
    if (MODE == 0) {
        #pragma unroll
        for (int r = 0; r < 8; ++r) amp[idx[r]] = v[r];
    } else if (MODE == 1) {
        __syncthreads();   // all reads done before cross-thread scatter
        #pragma unroll
        for (int r = 0; r < 8; ++r) amp[Sw(Fr(base | (r << PLOW)))] = v[r];
    } else {
        #pragma unroll
        for (int r = 0; r < 8; ++r) {
            const int x = Fr(base | (r << PLOW));   // final logical index
            const float p = v[r].x*v[r].x + v[r].y*v[r].y;
            #pragma unroll
            for (int q = 0; q < 12; ++q)
                zacc[q] += ((x >> (11 - q)) & 1) ? -p : p;
        }
    }
}

__global__ __launch_bounds__(NTH) void circuit_kernel(
    const float* __restrict__ qw,   // (3,12,3)
    const float* __restrict__ W1,   // (32,12)
    const float* __restrict__ b1,   // (32,)
    const float* __restrict__ W2,   // (16,32)
    const float* __restrict__ b2,   // (16,)
    float* __restrict__ pix)        // 16 outputs -> d_ws
{
    __shared__ float2 amp[4096];     // 32 KiB, swizzled storage
    __shared__ float4 gmat[36][2];   // U = RZ*RY*RX rows per gate
    __shared__ float  zp2[96];       // per-wave qubit partials (8 waves x 12)

    const int tid  = threadIdx.x;
    const int lane = tid & 63;
    const int wv   = tid >> 6;

    // ---- preload MLP weights early (latency hidden behind the circuit) ----
    float W1row[12], W2row[32], b1v = 0.f, b2v = 0.f;
    #pragma unroll
    for (int k = 0; k < 12; ++k) W1row[k] = 0.f;
    #pragma unroll
    for (int k = 0; k < 32; ++k) W2row[k] = 0.f;
    if (tid < 32) {
        b1v = b1[tid];
        #pragma unroll
        for (int k = 0; k < 12; ++k) W1row[k] = W1[tid*12 + k];
    }
    if (tid < 16) {
        b2v = b2[tid];
        #pragma unroll
        for (int k = 0; k < 32; ++k) W2row[k] = W2[tid*32 + k];
    }

    // ---- build the 36 gate matrices (one thread per gate) ----
    if (tid < 36) {
        float sx, cx, sy, cy, sz, cz;
        sincosf(0.5f * qw[tid*3+0], &sx, &cx);
        sincosf(0.5f * qw[tid*3+1], &sy, &cy);
        sincosf(0.5f * qw[tid*3+2], &sz, &cz);
        const float a00r =  cy*cx, a00i =  sy*sx;    // A = RY @ RX
        const float a01r = -sy*cx, a01i = -cy*sx;
        const float a10r =  sy*cx, a10i = -cy*sx;
        const float a11r =  cy*cx, a11i = -sy*sx;
        gmat[tid][0] = make_float4(cz*a00r + sz*a00i, cz*a00i - sz*a00r,
                                   cz*a01r + sz*a01i, cz*a01i - sz*a01r);
        gmat[tid][1] = make_float4(cz*a10r - sz*a10i, cz*a10i + sz*a10r,
                                   cz*a11r - sz*a11i, cz*a11i + sz*a11r);
    }
    __syncthreads();

    // ---- layer 1 = product state from |0..0>, built in registers; ring R1
    //      folded into the scatter write (verified R4) ----
    {
        float2 pp = make_float2(1.f, 0.f);
        #pragma unroll
        for (int b = 11; b >= 3; --b) {                 // i bit b = tid bit b-3
            const int q = 11 - b;
            const float4 g = gmat[q][(tid >> (b - 3)) & 1];
            pp = cmul(pp, make_float2(g.x, g.y));       // column 0
        }
        float2 c9[2], c10[2], c11[2];
        #pragma unroll
        for (int s = 0; s < 2; ++s) {
            c9[s]  = make_float2(gmat[9][s].x,  gmat[9][s].y);
            c10[s] = make_float2(gmat[10][s].x, gmat[10][s].y);
            c11[s] = make_float2(gmat[11][s].x, gmat[11][s].y);
        }
        #pragma unroll
        for (int r = 0; r < 8; ++r) {
            const float2 v = cmul(pp,
                cmul(c9[(r>>2)&1], cmul(c10[(r>>1)&1], c11[r&1])));
            amp[Sw(Fr((tid << 3) | r))] = v;
        }
    }
    __syncthreads();

    float zacc[12];
    #pragma unroll
    for (int q = 0; q < 12; ++q) zacc[q] = 0.f;

    // ---- layer 2 (gates 12..23): 4 passes, ring folded into the last ----
    do_pass<9,0>(amp, gmat, 12, tid, zacc); __syncthreads();
    do_pass<6,0>(amp, gmat, 12, tid, zacc); __syncthreads();
    do_pass<3,0>(amp, gmat, 12, tid, zacc); __syncthreads();
    do_pass<0,1>(amp, gmat, 12, tid, zacc); __syncthreads();
    // ---- layer 3 (gates 24..35): last pass emits partials, no writeback ----
    do_pass<9,0>(amp, gmat, 24, tid, zacc); __syncthreads();
    do_pass<6,0>(amp, gmat, 24, tid, zacc); __syncthreads();
    do_pass<3,0>(amp, gmat, 24, tid, zacc); __syncthreads();
    do_pass<0,2>(amp, gmat, 24, tid, zacc);

    // ---- in-wave reduction (verified R4) ----
    float z6[6];
    #pragma unroll
    for (int k = 0; k < 6; ++k) {
        const float send = (lane & 1) ? zacc[k]   : zacc[k+6];
        const float keep = (lane & 1) ? zacc[k+6] : zacc[k];
        z6[k] = keep + __shfl_xor(send, 1);
    }
    float z3[3];
    #pragma unroll
    for (int k = 0; k < 3; ++k) {
        const float send = (lane & 2) ? z6[k]   : z6[k+3];
        const float keep = (lane & 2) ? z6[k+3] : z6[k];
        z3[k] = keep + __shfl_xor(send, 2);
    }
    #pragma unroll
    for (int m = 4; m <= 32; m <<= 1) {
        #pragma unroll
        for (int k = 0; k < 3; ++k) z3[k] += __shfl_xor(z3[k], m);
    }
    if (lane < 4) {
        const int qb = 6*(lane & 1) + 3*((lane >> 1) & 1);
        #pragma unroll
        for (int k = 0; k < 3; ++k) zp2[wv*12 + qb + k] = z3[k];
    }
    __syncthreads();

    // ---- MLP entirely in wave 0 via shuffle broadcasts (verified R6) ----
    if (tid < 64) {
        float s = 0.f;
        if (tid < 12) {
            #pragma unroll
            for (int w8 = 0; w8 < 8; ++w8) s += zp2[w8*12 + tid];
        }
        float acc = b1v;                       // valid rows for lanes <32
        #pragma unroll
        for (int k = 0; k < 12; ++k) acc += W1row[k] * __shfl(s, k);
        const float h = acc > 0.f ? acc : 0.f;
        float acc2 = b2v;
        #pragma unroll
        for (int k = 0; k < 32; ++k) acc2 += W2row[k] * __shfl(h, k);
        if (tid < 16) pix[tid] = 1.f / (1.f + expf(-acc2));
    }
}

// ---------------------------------------------------------------------------
// Kernel B: broadcast 16 floats to (B,1,4,4) = 64 MiB, nontemporal stores
// via native clang vector type (HIP float4 is rejected by the builtin).
// ---------------------------------------------------------------------------
__global__ __launch_bounds__(256) void bcast_kernel(
    const v4f* __restrict__ pix4, v4f* __restrict__ out4)
{
    const int i = blockIdx.x * 256 + threadIdx.x;
    const v4f val = pix4[i & 3];
    __builtin_nontemporal_store(val, &out4[i]);
}

extern "C" void kernel_launch(void* const* d_in, const int* in_sizes, int n_in,
                              void* d_out, int out_size, void* d_ws, size_t ws_size,
                              hipStream_t stream) {
    // inputs: 0=images (ignored), 1=qweights, 2=W1, 3=b1, 4=W2, 5=b2
    const float* qw = (const float*)d_in[1];
    const float* W1 = (const float*)d_in[2];
    const float* b1 = (const float*)d_in[3];
    const float* W2 = (const float*)d_in[4];
    const float* b2 = (const float*)d_in[5];
    float* pix = (float*)d_ws;   // 16 floats of scratch

    circuit_kernel<<<1, NTH, 0, stream>>>(qw, W1, b1, W2, b2, pix);

    const int n4 = out_size / 4;               // 4,194,304 float4
    bcast_kernel<<<n4 / 256, 256, 0, stream>>>((const v4f*)pix,
                                               (v4f*)d_out);
}